// Round 1
// baseline (3019.532 us; speedup 1.0000x reference)
//
#include <hip/hip_runtime.h>
#include <hip/hip_bf16.h>
#include <math.h>

#define NN 100000
#define NE 1600000
#define D_IN 128
#define DH1 100
#define DH2 200
#define D_OUT 64

static inline int grid_for(long total, int block, long cap = 16384) {
    long b = (total + block - 1) / block;
    if (b > cap) b = cap;
    if (b < 1) b = 1;
    return (int)b;
}

// ---- degree computation: deg_out[src]++ , deg_in[dst]++ ----
__global__ void deg_kernel(const int* __restrict__ src, const int* __restrict__ dst,
                           float* __restrict__ deg_out, float* __restrict__ deg_in) {
    unsigned t = blockIdx.x * blockDim.x + threadIdx.x;
    unsigned stride = gridDim.x * blockDim.x;
    for (unsigned e = t; e < NE; e += stride) {
        atomicAdd(&deg_out[src[e]], 1.0f);
        atomicAdd(&deg_in[dst[e]], 1.0f);
    }
}

// ---- deg -> rsqrt(max(deg,1)) in place, both arrays ----
__global__ void norm_kernel(float* __restrict__ ns, float* __restrict__ nd) {
    unsigned t = blockIdx.x * blockDim.x + threadIdx.x;
    unsigned stride = gridDim.x * blockDim.x;
    for (unsigned n = t; n < NN; n += stride) {
        ns[n] = rsqrtf(fmaxf(ns[n], 1.0f));
        nd[n] = rsqrtf(fmaxf(nd[n], 1.0f));
    }
}

// ---- matmul with epilogue.
// EPI 0: out = acc * rowscale[n]
// EPI 1: out = elu(acc * rowscale[n] + bias[j])
template <int K, int J, int EPI>
__global__ void matmul_kernel(const float* __restrict__ in, const float* __restrict__ W,
                              const float* __restrict__ rowscale, const float* __restrict__ bias,
                              float* __restrict__ out) {
    unsigned total = (unsigned)NN * J;
    unsigned t0 = blockIdx.x * blockDim.x + threadIdx.x;
    unsigned stride = gridDim.x * blockDim.x;
    for (unsigned t = t0; t < total; t += stride) {
        unsigned n = t / J;
        unsigned j = t - n * J;
        const float* inr = in + (size_t)n * K;
        float acc = 0.0f;
#pragma unroll 8
        for (int k = 0; k < K; ++k) {
            acc += inr[k] * W[(size_t)k * J + j];
        }
        acc *= rowscale[n];
        if (EPI == 1) {
            acc += bias[j];
            acc = (acc > 0.0f) ? acc : expm1f(acc);
        }
        out[t] = acc;
    }
}

// ---- scatter-add over edges: agg[dst][f] += y[src][f] (* ns[src] if SCALE) ----
template <int D, bool SCALE_SRC>
__global__ void scatter_kernel(const float* __restrict__ y, const int* __restrict__ src,
                               const int* __restrict__ dst, const float* __restrict__ ns,
                               float* __restrict__ agg) {
    unsigned total = (unsigned)NE * D;
    unsigned t0 = blockIdx.x * blockDim.x + threadIdx.x;
    unsigned stride = gridDim.x * blockDim.x;
    for (unsigned t = t0; t < total; t += stride) {
        unsigned e = t / D;
        unsigned f = t - e * D;
        int s = src[e];
        int d = dst[e];
        float v = y[(size_t)s * D + f];
        if (SCALE_SRC) v *= ns[s];
        atomicAdd(&agg[(size_t)d * D + f], v);
    }
}

// ---- pointwise epilogue on aggregated buffer.
// ACT 0: x = elu(x*nd[n] + b[j])     ACT 1: x = sigmoid(x*nd[n] + b[j])
template <int J, int ACT>
__global__ void pointwise_kernel(float* __restrict__ buf, const float* __restrict__ nd,
                                 const float* __restrict__ bias) {
    unsigned total = (unsigned)NN * J;
    unsigned t0 = blockIdx.x * blockDim.x + threadIdx.x;
    unsigned stride = gridDim.x * blockDim.x;
    for (unsigned t = t0; t < total; t += stride) {
        unsigned n = t / J;
        unsigned j = t - n * J;
        float v = buf[t] * nd[n] + bias[j];
        if (ACT == 0) v = (v > 0.0f) ? v : expm1f(v);
        else          v = 1.0f / (1.0f + expf(-v));
        buf[t] = v;
    }
}

extern "C" void kernel_launch(void* const* d_in, const int* in_sizes, int n_in,
                              void* d_out, int out_size, void* d_ws, size_t ws_size,
                              hipStream_t stream) {
    const float* x    = (const float*)d_in[0];
    const int*   esrc = (const int*)d_in[1];
    const int*   edst = (const int*)d_in[2];
    const float* W1   = (const float*)d_in[3];
    const float* b1   = (const float*)d_in[4];
    const float* W2   = (const float*)d_in[5];
    const float* b2   = (const float*)d_in[6];
    const float* W3   = (const float*)d_in[7];
    const float* b3   = (const float*)d_in[8];
    float* out = (float*)d_out;

    // workspace layout (floats): A [NN*100], B [NN*200], ns [NN], nd [NN]
    float* A  = (float*)d_ws;
    float* B  = A + (size_t)NN * 100;
    float* ns = B + (size_t)NN * 200;
    float* nd = ns + NN;

    const int BLK = 256;

    // degrees -> norms
    hipMemsetAsync(ns, 0, 2 * (size_t)NN * sizeof(float), stream);
    deg_kernel<<<grid_for(NE, BLK), BLK, 0, stream>>>(esrc, edst, ns, nd);
    norm_kernel<<<grid_for(NN, BLK), BLK, 0, stream>>>(ns, nd);

    // L1: y1 = (x @ W1) * ns   -> A [NN,100]
    matmul_kernel<D_IN, DH1, 0><<<grid_for((long)NN * DH1, BLK), BLK, 0, stream>>>(
        x, W1, ns, nullptr, A);
    // agg1 = scatter(y1)       -> B [NN,100]
    hipMemsetAsync(B, 0, (size_t)NN * DH1 * sizeof(float), stream);
    scatter_kernel<DH1, false><<<grid_for((long)NE * DH1, BLK), BLK, 0, stream>>>(
        A, esrc, edst, nullptr, B);
    // h1 = elu(agg1*nd + b1)   in place in B
    pointwise_kernel<DH1, 0><<<grid_for((long)NN * DH1, BLK), BLK, 0, stream>>>(B, nd, b1);

    // L2: agg2 = scatter(h1 * ns) -> A [NN,100]
    hipMemsetAsync(A, 0, (size_t)NN * DH1 * sizeof(float), stream);
    scatter_kernel<DH1, true><<<grid_for((long)NE * DH1, BLK), BLK, 0, stream>>>(
        B, esrc, edst, ns, A);
    // h2 = elu((agg2 @ W2)*nd + b2) -> B [NN,200]
    matmul_kernel<DH1, DH2, 1><<<grid_for((long)NN * DH2, BLK), BLK, 0, stream>>>(
        A, W2, nd, b2, B);

    // L3: y3 = (h2 @ W3) * ns  -> A [NN,64]
    matmul_kernel<DH2, D_OUT, 0><<<grid_for((long)NN * D_OUT, BLK), BLK, 0, stream>>>(
        B, W3, ns, nullptr, A);
    // agg3 = scatter(y3)       -> out [NN,64]
    hipMemsetAsync(out, 0, (size_t)NN * D_OUT * sizeof(float), stream);
    scatter_kernel<D_OUT, false><<<grid_for((long)NE * D_OUT, BLK), BLK, 0, stream>>>(
        A, esrc, edst, nullptr, out);
    // out = sigmoid(out*nd + b3) in place
    pointwise_kernel<D_OUT, 1><<<grid_for((long)NN * D_OUT, BLK), BLK, 0, stream>>>(out, nd, b3);
}

// Round 2
// 2035.980 us; speedup vs baseline: 1.4831x; 1.4831x over previous
//
#include <hip/hip_runtime.h>
#include <hip/hip_bf16.h>
#include <math.h>

#define NN 100000
#define NE 1600000
#define D_IN 128
#define DH1 100
#define DH2 200
#define D_OUT 64

#define SCAN_BLK 256
#define NB_SCAN ((NN + SCAN_BLK - 1) / SCAN_BLK)   // 391

static inline int grid_for(long total, int block, long cap = 16384) {
    long b = (total + block - 1) / block;
    if (b > cap) b = cap;
    if (b < 1) b = 1;
    return (int)b;
}

// ---- degree histograms: cnt_src[src[e]]++, cnt_dst[dst[e]]++ ----
__global__ void hist_kernel(const int* __restrict__ src, const int* __restrict__ dst,
                            int* __restrict__ cnt_src, int* __restrict__ cnt_dst) {
    unsigned t = blockIdx.x * blockDim.x + threadIdx.x;
    unsigned stride = gridDim.x * blockDim.x;
    for (unsigned e = t; e < NE; e += stride) {
        atomicAdd(&cnt_src[src[e]], 1);
        atomicAdd(&cnt_dst[dst[e]], 1);
    }
}

// ---- norms from integer degrees ----
__global__ void norm_kernel(const int* __restrict__ cs, const int* __restrict__ cd,
                            float* __restrict__ ns, float* __restrict__ nd) {
    unsigned t = blockIdx.x * blockDim.x + threadIdx.x;
    unsigned stride = gridDim.x * blockDim.x;
    for (unsigned n = t; n < NN; n += stride) {
        ns[n] = rsqrtf(fmaxf((float)cs[n], 1.0f));
        nd[n] = rsqrtf(fmaxf((float)cd[n], 1.0f));
    }
}

// ---- scan step 1: per-block sums of cnt_dst ----
__global__ void block_sum_kernel(const int* __restrict__ cnt, int* __restrict__ partials) {
    __shared__ int sm[SCAN_BLK];
    int i = blockIdx.x * SCAN_BLK + threadIdx.x;
    sm[threadIdx.x] = (i < NN) ? cnt[i] : 0;
    __syncthreads();
    for (int s = SCAN_BLK / 2; s > 0; s >>= 1) {
        if (threadIdx.x < s) sm[threadIdx.x] += sm[threadIdx.x + s];
        __syncthreads();
    }
    if (threadIdx.x == 0) partials[blockIdx.x] = sm[0];
}

// ---- scan step 2: serial exclusive scan of 391 partials (trivial) ----
__global__ void scan_partials_kernel(int* __restrict__ partials) {
    if (blockIdx.x == 0 && threadIdx.x == 0) {
        int acc = 0;
        for (int i = 0; i < NB_SCAN; ++i) { int v = partials[i]; partials[i] = acc; acc += v; }
    }
}

// ---- scan step 3: in-block exclusive scan + offset -> row_ptr, fill_pos ----
__global__ void block_scan_kernel(const int* __restrict__ cnt, const int* __restrict__ partials,
                                  int* __restrict__ row_ptr, int* __restrict__ fill_pos) {
    __shared__ int sm[SCAN_BLK];
    int i = blockIdx.x * SCAN_BLK + threadIdx.x;
    int v = (i < NN) ? cnt[i] : 0;
    sm[threadIdx.x] = v;
    __syncthreads();
    for (int off = 1; off < SCAN_BLK; off <<= 1) {
        int t = (threadIdx.x >= off) ? sm[threadIdx.x - off] : 0;
        __syncthreads();
        sm[threadIdx.x] += t;
        __syncthreads();
    }
    if (i < NN) {
        int excl = partials[blockIdx.x] + sm[threadIdx.x] - v;
        row_ptr[i] = excl;
        fill_pos[i] = excl;
        if (i == NN - 1) row_ptr[NN] = excl + v;
    }
}

// ---- CSR bucket fill: col_src grouped by dst ----
__global__ void fill_kernel(const int* __restrict__ src, const int* __restrict__ dst,
                            int* __restrict__ fill_pos, int* __restrict__ col_src) {
    unsigned t = blockIdx.x * blockDim.x + threadIdx.x;
    unsigned stride = gridDim.x * blockDim.x;
    for (unsigned e = t; e < NE; e += stride) {
        int p = atomicAdd(&fill_pos[dst[e]], 1);
        col_src[p] = src[e];
    }
}

// ---- matmul with epilogue.
// EPI 0: out = acc * rowscale[n]
// EPI 1: out = elu(acc * rowscale[n] + bias[j])
template <int K, int J, int EPI>
__global__ void matmul_kernel(const float* __restrict__ in, const float* __restrict__ W,
                              const float* __restrict__ rowscale, const float* __restrict__ bias,
                              float* __restrict__ out) {
    unsigned total = (unsigned)NN * J;
    unsigned t0 = blockIdx.x * blockDim.x + threadIdx.x;
    unsigned stride = gridDim.x * blockDim.x;
    for (unsigned t = t0; t < total; t += stride) {
        unsigned n = t / J;
        unsigned j = t - n * J;
        const float* inr = in + (size_t)n * K;
        float acc = 0.0f;
#pragma unroll 8
        for (int k = 0; k < K; ++k) {
            acc += inr[k] * W[(size_t)k * J + j];
        }
        acc *= rowscale[n];
        if (EPI == 1) {
            acc += bias[j];
            acc = (acc > 0.0f) ? acc : expm1f(acc);
        }
        out[t] = acc;
    }
}

// ---- CSR gather-aggregate with fused epilogue.
// One thread per (node, feature). EPI:
//   0: out = acc                                  (feeds matmul which applies nd)
//   1: out = elu(acc*nd + b) * ns                 (hidden act, pre-scaled for next gather)
//   2: out = sigmoid(acc*nd + b)                  (final output)
template <int D, int EPI>
__global__ void gather_kernel(const float* __restrict__ y, const int* __restrict__ row_ptr,
                              const int* __restrict__ col_src,
                              const float* __restrict__ ns, const float* __restrict__ nd,
                              const float* __restrict__ bias, float* __restrict__ out) {
    unsigned t = blockIdx.x * blockDim.x + threadIdx.x;
    if (t >= (unsigned)NN * D) return;
    unsigned n = t / D;
    unsigned f = t - n * D;
    int start = row_ptr[n];
    int end = row_ptr[n + 1];
    float acc = 0.0f;
    for (int i = start; i < end; ++i) {
        int s = col_src[i];
        acc += y[(size_t)s * D + f];
    }
    if (EPI == 0) {
        out[t] = acc;
    } else if (EPI == 1) {
        float v = acc * nd[n] + bias[f];
        v = (v > 0.0f) ? v : expm1f(v);
        out[t] = v * ns[n];
    } else {
        float v = acc * nd[n] + bias[f];
        out[t] = 1.0f / (1.0f + expf(-v));
    }
}

extern "C" void kernel_launch(void* const* d_in, const int* in_sizes, int n_in,
                              void* d_out, int out_size, void* d_ws, size_t ws_size,
                              hipStream_t stream) {
    const float* x    = (const float*)d_in[0];
    const int*   esrc = (const int*)d_in[1];
    const int*   edst = (const int*)d_in[2];
    const float* W1   = (const float*)d_in[3];
    const float* b1   = (const float*)d_in[4];
    const float* W2   = (const float*)d_in[5];
    const float* b2   = (const float*)d_in[6];
    const float* W3   = (const float*)d_in[7];
    const float* b3   = (const float*)d_in[8];
    float* out = (float*)d_out;

    // workspace layout
    float* A        = (float*)d_ws;                       // [NN*100]
    float* B        = A + (size_t)NN * DH1;               // [NN*200]
    float* ns       = B + (size_t)NN * DH2;               // [NN]
    float* nd       = ns + NN;                            // [NN]
    int*   cnt_src  = (int*)(nd + NN);                    // [NN]
    int*   cnt_dst  = cnt_src + NN;                       // [NN]
    int*   row_ptr  = cnt_dst + NN;                       // [NN+1]
    int*   fill_pos = row_ptr + NN + 1;                   // [NN]
    int*   col_src  = fill_pos + NN;                      // [NE]
    int*   partials = col_src + NE;                       // [NB_SCAN]

    const int BLK = 256;

    // ---- graph preprocessing: degrees, norms, dst-CSR ----
    hipMemsetAsync(cnt_src, 0, 2 * (size_t)NN * sizeof(int), stream);
    hist_kernel<<<grid_for(NE, BLK), BLK, 0, stream>>>(esrc, edst, cnt_src, cnt_dst);
    norm_kernel<<<grid_for(NN, BLK), BLK, 0, stream>>>(cnt_src, cnt_dst, ns, nd);
    block_sum_kernel<<<NB_SCAN, SCAN_BLK, 0, stream>>>(cnt_dst, partials);
    scan_partials_kernel<<<1, 64, 0, stream>>>(partials);
    block_scan_kernel<<<NB_SCAN, SCAN_BLK, 0, stream>>>(cnt_dst, partials, row_ptr, fill_pos);
    fill_kernel<<<grid_for(NE, BLK), BLK, 0, stream>>>(esrc, edst, fill_pos, col_src);

    // ---- L1: y1 = (x @ W1) * ns -> A [NN,100] ----
    matmul_kernel<D_IN, DH1, 0><<<grid_for((long)NN * DH1, BLK), BLK, 0, stream>>>(
        x, W1, ns, nullptr, A);
    // h1s = elu(gather(y1)*nd + b1) * ns -> B [NN,100]
    gather_kernel<DH1, 1><<<grid_for((long)NN * DH1, BLK, 1 << 30), BLK, 0, stream>>>(
        A, row_ptr, col_src, ns, nd, b1, B);

    // ---- L2: agg2 = gather(h1s) -> A [NN,100] ----
    gather_kernel<DH1, 0><<<grid_for((long)NN * DH1, BLK, 1 << 30), BLK, 0, stream>>>(
        B, row_ptr, col_src, ns, nd, nullptr, A);
    // h2 = elu((agg2 @ W2)*nd + b2) -> B [NN,200]
    matmul_kernel<DH1, DH2, 1><<<grid_for((long)NN * DH2, BLK), BLK, 0, stream>>>(
        A, W2, nd, b2, B);

    // ---- L3: y3 = (h2 @ W3) * ns -> A [NN,64] ----
    matmul_kernel<DH2, D_OUT, 0><<<grid_for((long)NN * D_OUT, BLK), BLK, 0, stream>>>(
        B, W3, ns, nullptr, A);
    // out = sigmoid(gather(y3)*nd + b3)
    gather_kernel<D_OUT, 2><<<grid_for((long)NN * D_OUT, BLK, 1 << 30), BLK, 0, stream>>>(
        A, row_ptr, col_src, ns, nd, b3, out);
}

// Round 5
// 716.270 us; speedup vs baseline: 4.2156x; 2.8425x over previous
//
#include <hip/hip_runtime.h>
#include <hip/hip_bf16.h>
#include <math.h>

#define NN 100000
#define NE 1600000

#define SCAN_BLK 256
#define NB_SCAN ((NN + SCAN_BLK - 1) / SCAN_BLK)   // 391

typedef float f32x4 __attribute__((ext_vector_type(4)));
typedef short s16x8 __attribute__((ext_vector_type(8)));
typedef unsigned short u16x4 __attribute__((ext_vector_type(4)));

static inline int grid_for(long total, int block, long cap = 16384) {
    long b = (total + block - 1) / block;
    if (b > cap) b = cap;
    if (b < 1) b = 1;
    return (int)b;
}

__device__ __forceinline__ unsigned short f2b(float f) {
    __hip_bfloat16 h = __float2bfloat16(f);   // round-to-nearest
    return __builtin_bit_cast(unsigned short, h);
}
__device__ __forceinline__ float b2f(unsigned short u) {
    unsigned int x = ((unsigned int)u) << 16;
    return __builtin_bit_cast(float, x);
}

// ================= graph preprocessing =================

__global__ void hist_kernel(const int* __restrict__ src, const int* __restrict__ dst,
                            int* __restrict__ cnt_src, int* __restrict__ cnt_dst) {
    unsigned t = blockIdx.x * blockDim.x + threadIdx.x;
    unsigned stride = gridDim.x * blockDim.x;
    for (unsigned e = t; e < NE; e += stride) {
        atomicAdd(&cnt_src[src[e]], 1);
        atomicAdd(&cnt_dst[dst[e]], 1);
    }
}

__global__ void norm_kernel(const int* __restrict__ cs, const int* __restrict__ cd,
                            float* __restrict__ ns, float* __restrict__ nd) {
    unsigned t = blockIdx.x * blockDim.x + threadIdx.x;
    unsigned stride = gridDim.x * blockDim.x;
    for (unsigned n = t; n < NN; n += stride) {
        ns[n] = rsqrtf(fmaxf((float)cs[n], 1.0f));
        nd[n] = rsqrtf(fmaxf((float)cd[n], 1.0f));
    }
}

__global__ void block_sum_kernel(const int* __restrict__ cnt, int* __restrict__ partials) {
    __shared__ int sm[SCAN_BLK];
    int i = blockIdx.x * SCAN_BLK + threadIdx.x;
    sm[threadIdx.x] = (i < NN) ? cnt[i] : 0;
    __syncthreads();
    for (int s = SCAN_BLK / 2; s > 0; s >>= 1) {
        if (threadIdx.x < s) sm[threadIdx.x] += sm[threadIdx.x + s];
        __syncthreads();
    }
    if (threadIdx.x == 0) partials[blockIdx.x] = sm[0];
}

// single-block parallel exclusive scan of NB_SCAN partials (512 threads)
__global__ void scan_partials_kernel(int* __restrict__ p) {
    __shared__ int sm[512];
    int tid = threadIdx.x;
    int v = (tid < NB_SCAN) ? p[tid] : 0;
    sm[tid] = v;
    __syncthreads();
    for (int off = 1; off < 512; off <<= 1) {
        int t = (tid >= off) ? sm[tid - off] : 0;
        __syncthreads();
        sm[tid] += t;
        __syncthreads();
    }
    if (tid < NB_SCAN) p[tid] = sm[tid] - v;   // exclusive
}

__global__ void block_scan_kernel(const int* __restrict__ cnt, const int* __restrict__ partials,
                                  int* __restrict__ row_ptr, int* __restrict__ fill_pos) {
    __shared__ int sm[SCAN_BLK];
    int i = blockIdx.x * SCAN_BLK + threadIdx.x;
    int v = (i < NN) ? cnt[i] : 0;
    sm[threadIdx.x] = v;
    __syncthreads();
    for (int off = 1; off < SCAN_BLK; off <<= 1) {
        int t = (threadIdx.x >= off) ? sm[threadIdx.x - off] : 0;
        __syncthreads();
        sm[threadIdx.x] += t;
        __syncthreads();
    }
    if (i < NN) {
        int excl = partials[blockIdx.x] + sm[threadIdx.x] - v;
        row_ptr[i] = excl;
        fill_pos[i] = excl;
        if (i == NN - 1) row_ptr[NN] = excl + v;
    }
}

__global__ void fill_kernel(const int* __restrict__ src, const int* __restrict__ dst,
                            int* __restrict__ fill_pos, int* __restrict__ col_src) {
    unsigned t = blockIdx.x * blockDim.x + threadIdx.x;
    unsigned stride = gridDim.x * blockDim.x;
    for (unsigned e = t; e < NE; e += stride) {
        int p = atomicAdd(&fill_pos[dst[e]], 1);
        col_src[p] = src[e];
    }
}

// ================= bf16 prep =================

// f32 -> bf16, 4 at a time
__global__ void f32_to_bf16_kernel(const float* __restrict__ in, unsigned short* __restrict__ out,
                                   int n4) {
    int t = blockIdx.x * blockDim.x + threadIdx.x;
    if (t >= n4) return;
    f32x4 v = reinterpret_cast<const f32x4*>(in)[t];
    u16x4 o;
#pragma unroll
    for (int j = 0; j < 4; ++j) o[j] = f2b(v[j]);
    reinterpret_cast<u16x4*>(out)[t] = o;
}

// W [K_REAL][N_REAL] f32 -> fragment-packed bf16 (zero-padded).
// Wf[frag*512 + lane*8 + j] = W[kt*32 + (lane>>4)*8 + j][nt*16 + (lane&15)]
template <int K_REAL, int N_REAL, int NTILES>
__global__ void repack_kernel(const float* __restrict__ W, unsigned short* __restrict__ Wf,
                              int total) {
    int t = blockIdx.x * blockDim.x + threadIdx.x;
    if (t >= total) return;
    int j = t & 7, lane = (t >> 3) & 63, frag = t >> 9;
    int kt = frag / NTILES, nt = frag - kt * NTILES;
    int k = kt * 32 + (lane >> 4) * 8 + j;
    int n = nt * 16 + (lane & 15);
    float v = (k < K_REAL && n < N_REAL) ? W[(size_t)k * N_REAL + n] : 0.0f;
    Wf[t] = f2b(v);
}

__global__ void padbias_kernel(const float* __restrict__ b, float* __restrict__ bp,
                               int nreal, int npad) {
    int t = blockIdx.x * blockDim.x + threadIdx.x;
    if (t < npad) bp[t] = (t < nreal) ? b[t] : 0.0f;
}

// ================= MFMA GEMM =================
// A: [NN][K_PAD] bf16 row-major. Wf: fragment-packed. Each wave: 16 rows, all N.
// EPI 0: f32 out[row*N_REAL + col] = acc * rowscale[row]   (store only col < N_REAL)
// EPI 1: bf16 out[row*(NTILES*16) + col] = elu(acc * rowscale[row] + bias[col])
template <int K_STEPS, int NTILES, int N_REAL, int EPI, int K_PAD>
__global__ __launch_bounds__(256) void gemm_kernel(
    const unsigned short* __restrict__ Abf, const unsigned short* __restrict__ Wf,
    const float* __restrict__ rowscale, const float* __restrict__ bias,
    void* __restrict__ outv)
{
    int wave = blockIdx.x * (blockDim.x >> 6) + (threadIdx.x >> 6);
    int row0 = wave << 4;
    if (row0 >= NN) return;
    int lane = threadIdx.x & 63;
    int r = lane & 15, half = lane >> 4;

    f32x4 acc[NTILES];
#pragma unroll
    for (int nt = 0; nt < NTILES; ++nt) acc[nt] = (f32x4)(0.0f);

    const unsigned short* arow = Abf + (size_t)(row0 + r) * K_PAD + half * 8;
#pragma unroll
    for (int kt = 0; kt < K_STEPS; ++kt) {
        s16x8 a = *reinterpret_cast<const s16x8*>(arow + kt * 32);
#pragma unroll
        for (int nt = 0; nt < NTILES; ++nt) {
            s16x8 b = *reinterpret_cast<const s16x8*>(
                Wf + (((kt * NTILES + nt) << 9) | (lane << 3)));
            acc[nt] = __builtin_amdgcn_mfma_f32_16x16x32_bf16(a, b, acc[nt], 0, 0, 0);
        }
    }

    int colbase = lane & 15;
    float rs[4];
#pragma unroll
    for (int j = 0; j < 4; ++j) rs[j] = rowscale[row0 + half * 4 + j];

    if (EPI == 0) {
        float* out = (float*)outv;
#pragma unroll
        for (int nt = 0; nt < NTILES; ++nt) {
            int col = nt * 16 + colbase;
            if (col < N_REAL) {
#pragma unroll
                for (int j = 0; j < 4; ++j) {
                    int row = row0 + half * 4 + j;
                    out[(size_t)row * N_REAL + col] = acc[nt][j] * rs[j];
                }
            }
        }
    } else {
        unsigned short* out = (unsigned short*)outv;
        const int NOUT = NTILES * 16;
#pragma unroll
        for (int nt = 0; nt < NTILES; ++nt) {
            int col = nt * 16 + colbase;
            float bv = bias[col];
#pragma unroll
            for (int j = 0; j < 4; ++j) {
                int row = row0 + half * 4 + j;
                float v = acc[nt][j] * rs[j] + bv;
                v = (v > 0.0f) ? v : expm1f(v);
                out[(size_t)row * NOUT + col] = f2b(v);
            }
        }
    }
}

// ================= gathers (float4-vectorized) =================

// gather1: y1 f32 [NN][100] -> h1s bf16 [NN][100];  h1s = elu(sum*nd + b1) * ns
__global__ void gather1_kernel(const float* __restrict__ y, const int* __restrict__ row_ptr,
                               const int* __restrict__ col_src, const float* __restrict__ ns,
                               const float* __restrict__ nd, const float* __restrict__ bias,
                               unsigned short* __restrict__ out) {
    unsigned t = blockIdx.x * blockDim.x + threadIdx.x;
    if (t >= NN * 25u) return;
    unsigned n = t / 25u, g = t - n * 25u;
    int start = row_ptr[n], end = row_ptr[n + 1];
    f32x4 acc = (f32x4)(0.0f);
    for (int i = start; i < end; ++i) {
        int s = col_src[i];
        acc += *reinterpret_cast<const f32x4*>(y + (size_t)s * 100 + g * 4);
    }
    f32x4 b4 = *reinterpret_cast<const f32x4*>(bias + g * 4);
    float ndv = nd[n], nsv = ns[n];
    u16x4 o;
#pragma unroll
    for (int j = 0; j < 4; ++j) {
        float v = acc[j] * ndv + b4[j];
        v = (v > 0.0f) ? v : expm1f(v);
        o[j] = f2b(v * nsv);
    }
    *reinterpret_cast<u16x4*>(out + (size_t)n * 100 + g * 4) = o;
}

// gather2: h1s bf16 [NN][100] -> agg2b bf16 [NN][128] (raw sums, cols 0..99)
__global__ void gather2_kernel(const unsigned short* __restrict__ y, const int* __restrict__ row_ptr,
                               const int* __restrict__ col_src, unsigned short* __restrict__ out) {
    unsigned t = blockIdx.x * blockDim.x + threadIdx.x;
    if (t >= NN * 25u) return;
    unsigned n = t / 25u, g = t - n * 25u;
    int start = row_ptr[n], end = row_ptr[n + 1];
    f32x4 acc = (f32x4)(0.0f);
    for (int i = start; i < end; ++i) {
        int s = col_src[i];
        u16x4 v = *reinterpret_cast<const u16x4*>(y + (size_t)s * 100 + g * 4);
#pragma unroll
        for (int j = 0; j < 4; ++j) acc[j] += b2f(v[j]);
    }
    u16x4 o;
#pragma unroll
    for (int j = 0; j < 4; ++j) o[j] = f2b(acc[j]);
    *reinterpret_cast<u16x4*>(out + (size_t)n * 128 + g * 4) = o;
}

// gather3: y3 f32 [NN][64] -> out f32 [NN][64];  out = sigmoid(sum*nd + b3)
__global__ void gather3_kernel(const float* __restrict__ y, const int* __restrict__ row_ptr,
                               const int* __restrict__ col_src, const float* __restrict__ nd,
                               const float* __restrict__ bias, float* __restrict__ out) {
    unsigned t = blockIdx.x * blockDim.x + threadIdx.x;
    if (t >= NN * 16u) return;
    unsigned n = t >> 4, g = t & 15u;
    int start = row_ptr[n], end = row_ptr[n + 1];
    f32x4 acc = (f32x4)(0.0f);
    for (int i = start; i < end; ++i) {
        int s = col_src[i];
        acc += *reinterpret_cast<const f32x4*>(y + (size_t)s * 64 + g * 4);
    }
    f32x4 b4 = *reinterpret_cast<const f32x4*>(bias + g * 4);
    float ndv = nd[n];
    f32x4 o;
#pragma unroll
    for (int j = 0; j < 4; ++j) {
        float v = acc[j] * ndv + b4[j];
        o[j] = 1.0f / (1.0f + expf(-v));
    }
    *reinterpret_cast<f32x4*>(out + (size_t)n * 64 + g * 4) = o;
}

// ================= launch =================

extern "C" void kernel_launch(void* const* d_in, const int* in_sizes, int n_in,
                              void* d_out, int out_size, void* d_ws, size_t ws_size,
                              hipStream_t stream) {
    const float* x    = (const float*)d_in[0];
    const int*   esrc = (const int*)d_in[1];
    const int*   edst = (const int*)d_in[2];
    const float* W1   = (const float*)d_in[3];
    const float* b1   = (const float*)d_in[4];
    const float* W2   = (const float*)d_in[5];
    const float* b2   = (const float*)d_in[6];
    const float* W3   = (const float*)d_in[7];
    const float* b3   = (const float*)d_in[8];
    float* out = (float*)d_out;

    // ---- workspace carving (256B-aligned regions) ----
    char* base = (char*)d_ws;
    size_t off = 0;
    auto alloc = [&](size_t bytes) -> void* {
        void* p = base + off;
        off += (bytes + 255) & ~(size_t)255;
        return p;
    };
    // region1: xb (bf16 [NN][128]) -> agg2b (bf16 [NN][128]) -> y3 (f32 [NN][64])
    void* region1 = alloc((size_t)NN * 128 * 2);
    // region2: y1 (f32 [NN][100]) -> h2b (bf16 [NN][224])
    void* region2 = alloc((size_t)NN * 224 * 2);
    // region3: h1s (bf16 [NN][100])
    void* region3 = alloc((size_t)NN * 100 * 2);
    float* ns       = (float*)alloc(NN * 4);
    float* nd       = (float*)alloc(NN * 4);
    int*   cnt_src  = (int*)alloc(NN * 4);
    int*   cnt_dst  = (int*)alloc(NN * 4);
    int*   row_ptr  = (int*)alloc((NN + 1) * 4);
    int*   fill_pos = (int*)alloc(NN * 4);
    int*   col_src  = (int*)alloc((size_t)NE * 4);
    int*   partials = (int*)alloc(512 * 4);
    unsigned short* W1f = (unsigned short*)alloc(4 * 7 * 512 * 2);    // K=128,N=112
    unsigned short* W2f = (unsigned short*)alloc(4 * 14 * 512 * 2);   // K=128,N=224
    unsigned short* W3f = (unsigned short*)alloc(7 * 4 * 512 * 2);    // K=224,N=64
    float* b2p = (float*)alloc(224 * 4);

    unsigned short* xb    = (unsigned short*)region1;
    unsigned short* agg2b = (unsigned short*)region1;
    float*          y3    = (float*)region1;
    float*          y1    = (float*)region2;
    unsigned short* h2b   = (unsigned short*)region2;
    unsigned short* h1s   = (unsigned short*)region3;

    const int BLK = 256;
    const int GEMM_GRID = (NN / 16 + 3) / 4;   // 6250 waves / 4 per block = 1563

    // ---- graph preprocessing ----
    hipMemsetAsync(cnt_src, 0, (size_t)NN * 4, stream);
    hipMemsetAsync(cnt_dst, 0, (size_t)NN * 4, stream);
    hist_kernel<<<grid_for(NE, BLK), BLK, 0, stream>>>(esrc, edst, cnt_src, cnt_dst);
    norm_kernel<<<grid_for(NN, BLK), BLK, 0, stream>>>(cnt_src, cnt_dst, ns, nd);
    block_sum_kernel<<<NB_SCAN, SCAN_BLK, 0, stream>>>(cnt_dst, partials);
    scan_partials_kernel<<<1, 512, 0, stream>>>(partials);
    block_scan_kernel<<<NB_SCAN, SCAN_BLK, 0, stream>>>(cnt_dst, partials, row_ptr, fill_pos);
    fill_kernel<<<grid_for(NE, BLK), BLK, 0, stream>>>(esrc, edst, fill_pos, col_src);

    // ---- bf16 prep ----
    f32_to_bf16_kernel<<<grid_for((long)NN * 128 / 4, BLK, 1 << 30), BLK, 0, stream>>>(
        x, xb, NN * 128 / 4);
    repack_kernel<128, 100, 7><<<grid_for(28 * 512, BLK), BLK, 0, stream>>>(W1, W1f, 28 * 512);
    repack_kernel<100, 200, 14><<<grid_for(56 * 512, BLK), BLK, 0, stream>>>(W2, W2f, 56 * 512);
    repack_kernel<200, 64, 4><<<grid_for(28 * 512, BLK), BLK, 0, stream>>>(W3, W3f, 28 * 512);
    padbias_kernel<<<1, 256, 0, stream>>>(b2, b2p, 200, 224);

    // ---- L1: y1 = (x @ W1) * ns  (f32 [NN][100]) ----
    gemm_kernel<4, 7, 100, 0, 128><<<GEMM_GRID, BLK, 0, stream>>>(xb, W1f, ns, nullptr, y1);
    // h1s = elu(gather(y1)*nd + b1) * ns  (bf16 [NN][100])
    gather1_kernel<<<grid_for((long)NN * 25, BLK, 1 << 30), BLK, 0, stream>>>(
        y1, row_ptr, col_src, ns, nd, b1, h1s);

    // ---- L2: agg2 = gather(h1s)  (bf16 [NN][128], zero-padded) ----
    hipMemsetAsync(agg2b, 0, (size_t)NN * 128 * 2, stream);
    gather2_kernel<<<grid_for((long)NN * 25, BLK, 1 << 30), BLK, 0, stream>>>(
        h1s, row_ptr, col_src, agg2b);
    // h2 = elu((agg2 @ W2)*nd + b2)  (bf16 [NN][224], pads auto-zero)
    gemm_kernel<4, 14, 200, 1, 128><<<GEMM_GRID, BLK, 0, stream>>>(agg2b, W2f, nd, b2p, h2b);

    // ---- L3: y3 = (h2 @ W3) * ns  (f32 [NN][64]) ----
    gemm_kernel<7, 4, 64, 0, 224><<<GEMM_GRID, BLK, 0, stream>>>(h2b, W3f, ns, nullptr, y3);
    // out = sigmoid(gather(y3)*nd + b3)
    gather3_kernel<<<grid_for((long)NN * 16, BLK, 1 << 30), BLK, 0, stream>>>(
        y3, row_ptr, col_src, nd, b3, out);
}

// Round 6
// 628.229 us; speedup vs baseline: 4.8064x; 1.1401x over previous
//
#include <hip/hip_runtime.h>
#include <hip/hip_bf16.h>
#include <math.h>

#define NN 100000
#define NE 1600000

#define SCAN_BLK 256
#define NB_SCAN ((NN + SCAN_BLK - 1) / SCAN_BLK)   // 391

typedef float f32x4 __attribute__((ext_vector_type(4)));
typedef short s16x8 __attribute__((ext_vector_type(8)));
typedef unsigned short u16x4 __attribute__((ext_vector_type(4)));

static inline int grid_for(long total, int block, long cap = 16384) {
    long b = (total + block - 1) / block;
    if (b > cap) b = cap;
    if (b < 1) b = 1;
    return (int)b;
}

__device__ __forceinline__ unsigned short f2b(float f) {
    __hip_bfloat16 h = __float2bfloat16(f);   // round-to-nearest
    return __builtin_bit_cast(unsigned short, h);
}
__device__ __forceinline__ float b2f(unsigned short u) {
    unsigned int x = ((unsigned int)u) << 16;
    return __builtin_bit_cast(float, x);
}

// ================= graph preprocessing =================

__global__ void hist_kernel(const int* __restrict__ src, const int* __restrict__ dst,
                            int* __restrict__ cnt_src, int* __restrict__ cnt_dst) {
    unsigned t = blockIdx.x * blockDim.x + threadIdx.x;
    unsigned stride = gridDim.x * blockDim.x;
    for (unsigned e = t; e < NE; e += stride) {
        atomicAdd(&cnt_src[src[e]], 1);
        atomicAdd(&cnt_dst[dst[e]], 1);
    }
}

__global__ void norm_kernel(const int* __restrict__ cs, const int* __restrict__ cd,
                            float* __restrict__ ns, float* __restrict__ nd) {
    unsigned t = blockIdx.x * blockDim.x + threadIdx.x;
    unsigned stride = gridDim.x * blockDim.x;
    for (unsigned n = t; n < NN; n += stride) {
        ns[n] = rsqrtf(fmaxf((float)cs[n], 1.0f));
        nd[n] = rsqrtf(fmaxf((float)cd[n], 1.0f));
    }
}

__global__ void block_sum_kernel(const int* __restrict__ cnt, int* __restrict__ partials) {
    __shared__ int sm[SCAN_BLK];
    int i = blockIdx.x * SCAN_BLK + threadIdx.x;
    sm[threadIdx.x] = (i < NN) ? cnt[i] : 0;
    __syncthreads();
    for (int s = SCAN_BLK / 2; s > 0; s >>= 1) {
        if (threadIdx.x < s) sm[threadIdx.x] += sm[threadIdx.x + s];
        __syncthreads();
    }
    if (threadIdx.x == 0) partials[blockIdx.x] = sm[0];
}

// single-block parallel exclusive scan of NB_SCAN partials (512 threads)
__global__ void scan_partials_kernel(int* __restrict__ p) {
    __shared__ int sm[512];
    int tid = threadIdx.x;
    int v = (tid < NB_SCAN) ? p[tid] : 0;
    sm[tid] = v;
    __syncthreads();
    for (int off = 1; off < 512; off <<= 1) {
        int t = (tid >= off) ? sm[tid - off] : 0;
        __syncthreads();
        sm[tid] += t;
        __syncthreads();
    }
    if (tid < NB_SCAN) p[tid] = sm[tid] - v;   // exclusive
}

__global__ void block_scan_kernel(const int* __restrict__ cnt, const int* __restrict__ partials,
                                  int* __restrict__ row_ptr, int* __restrict__ fill_pos) {
    __shared__ int sm[SCAN_BLK];
    int i = blockIdx.x * SCAN_BLK + threadIdx.x;
    int v = (i < NN) ? cnt[i] : 0;
    sm[threadIdx.x] = v;
    __syncthreads();
    for (int off = 1; off < SCAN_BLK; off <<= 1) {
        int t = (threadIdx.x >= off) ? sm[threadIdx.x - off] : 0;
        __syncthreads();
        sm[threadIdx.x] += t;
        __syncthreads();
    }
    if (i < NN) {
        int excl = partials[blockIdx.x] + sm[threadIdx.x] - v;
        row_ptr[i] = excl;
        fill_pos[i] = excl;
        if (i == NN - 1) row_ptr[NN] = excl + v;
    }
}

// XCD-bucketed CSR fill: blocks with blockIdx%8==b handle dst in bucket b only.
// All writes to bucket b's col_src region come from (heuristically) one XCD ->
// region stays L2-resident, lines fill completely before writeback.
__global__ void fill_bucketed_kernel(const int* __restrict__ src, const int* __restrict__ dst,
                                     int* __restrict__ fill_pos, int* __restrict__ col_src) {
    int b = blockIdx.x & 7;
    int lo = b * (NN / 8);
    int hi = lo + (NN / 8);          // NN/8 = 12500 exact
    unsigned t = (blockIdx.x >> 3) * blockDim.x + threadIdx.x;
    unsigned stride = (gridDim.x >> 3) * blockDim.x;
    for (unsigned e = t; e < NE; e += stride) {
        int d = dst[e];
        if (d >= lo && d < hi) {
            int p = atomicAdd(&fill_pos[d], 1);
            col_src[p] = src[e];
        }
    }
}

// ================= bf16 prep =================

// f32 -> bf16, 4 at a time
__global__ void f32_to_bf16_kernel(const float* __restrict__ in, unsigned short* __restrict__ out,
                                   int n4) {
    int t = blockIdx.x * blockDim.x + threadIdx.x;
    if (t >= n4) return;
    f32x4 v = reinterpret_cast<const f32x4*>(in)[t];
    u16x4 o;
#pragma unroll
    for (int j = 0; j < 4; ++j) o[j] = f2b(v[j]);
    reinterpret_cast<u16x4*>(out)[t] = o;
}

// W [K_REAL][N_REAL] f32 -> fragment-packed bf16 (zero-padded).
// Wf[frag*512 + lane*8 + j] = W[kt*32 + (lane>>4)*8 + j][nt*16 + (lane&15)]
template <int K_REAL, int N_REAL, int NTILES>
__global__ void repack_kernel(const float* __restrict__ W, unsigned short* __restrict__ Wf,
                              int total) {
    int t = blockIdx.x * blockDim.x + threadIdx.x;
    if (t >= total) return;
    int j = t & 7, lane = (t >> 3) & 63, frag = t >> 9;
    int kt = frag / NTILES, nt = frag - kt * NTILES;
    int k = kt * 32 + (lane >> 4) * 8 + j;
    int n = nt * 16 + (lane & 15);
    float v = (k < K_REAL && n < N_REAL) ? W[(size_t)k * N_REAL + n] : 0.0f;
    Wf[t] = f2b(v);
}

__global__ void padbias_kernel(const float* __restrict__ b, float* __restrict__ bp,
                               int nreal, int npad) {
    int t = blockIdx.x * blockDim.x + threadIdx.x;
    if (t < npad) bp[t] = (t < nreal) ? b[t] : 0.0f;
}

// ================= MFMA GEMM =================
// A: [NN][K_PAD] bf16 row-major. Wf: fragment-packed. Each wave: 16 rows, all N.
// EPI 1: bf16 out[row*(NTILES*16) + col] = elu(acc * rowscale[row] + bias[col])
// EPI 2: bf16 out[row*N_REAL + col]    = acc * rowscale[row]   (col < N_REAL only)
template <int K_STEPS, int NTILES, int N_REAL, int EPI, int K_PAD>
__global__ __launch_bounds__(256) void gemm_kernel(
    const unsigned short* __restrict__ Abf, const unsigned short* __restrict__ Wf,
    const float* __restrict__ rowscale, const float* __restrict__ bias,
    void* __restrict__ outv)
{
    int wave = blockIdx.x * (blockDim.x >> 6) + (threadIdx.x >> 6);
    int row0 = wave << 4;
    if (row0 >= NN) return;
    int lane = threadIdx.x & 63;
    int r = lane & 15, half = lane >> 4;

    f32x4 acc[NTILES];
#pragma unroll
    for (int nt = 0; nt < NTILES; ++nt) acc[nt] = (f32x4)(0.0f);

    const unsigned short* arow = Abf + (size_t)(row0 + r) * K_PAD + half * 8;
#pragma unroll
    for (int kt = 0; kt < K_STEPS; ++kt) {
        s16x8 a = *reinterpret_cast<const s16x8*>(arow + kt * 32);
#pragma unroll
        for (int nt = 0; nt < NTILES; ++nt) {
            s16x8 b = *reinterpret_cast<const s16x8*>(
                Wf + (((kt * NTILES + nt) << 9) | (lane << 3)));
            acc[nt] = __builtin_amdgcn_mfma_f32_16x16x32_bf16(a, b, acc[nt], 0, 0, 0);
        }
    }

    int colbase = lane & 15;
    float rs[4];
#pragma unroll
    for (int j = 0; j < 4; ++j) rs[j] = rowscale[row0 + half * 4 + j];

    if (EPI == 2) {
        unsigned short* out = (unsigned short*)outv;
#pragma unroll
        for (int nt = 0; nt < NTILES; ++nt) {
            int col = nt * 16 + colbase;
            if (col < N_REAL) {
#pragma unroll
                for (int j = 0; j < 4; ++j) {
                    int row = row0 + half * 4 + j;
                    out[(size_t)row * N_REAL + col] = f2b(acc[nt][j] * rs[j]);
                }
            }
        }
    } else {
        unsigned short* out = (unsigned short*)outv;
        const int NOUT = NTILES * 16;
#pragma unroll
        for (int nt = 0; nt < NTILES; ++nt) {
            int col = nt * 16 + colbase;
            float bv = bias[col];
#pragma unroll
            for (int j = 0; j < 4; ++j) {
                int row = row0 + half * 4 + j;
                float v = acc[nt][j] * rs[j] + bv;
                v = (v > 0.0f) ? v : expm1f(v);
                out[(size_t)row * NOUT + col] = f2b(v);
            }
        }
    }
}

// ================= gathers (vectorized) =================

// gather1: y1 bf16 [NN][100] -> h1s bf16 [NN][100];  h1s = elu(sum*nd + b1) * ns
__global__ void gather1_kernel(const unsigned short* __restrict__ y, const int* __restrict__ row_ptr,
                               const int* __restrict__ col_src, const float* __restrict__ ns,
                               const float* __restrict__ nd, const float* __restrict__ bias,
                               unsigned short* __restrict__ out) {
    unsigned t = blockIdx.x * blockDim.x + threadIdx.x;
    if (t >= NN * 25u) return;
    unsigned n = t / 25u, g = t - n * 25u;
    int start = row_ptr[n], end = row_ptr[n + 1];
    f32x4 acc = (f32x4)(0.0f);
    for (int i = start; i < end; ++i) {
        int s = col_src[i];
        u16x4 v = *reinterpret_cast<const u16x4*>(y + (size_t)s * 100 + g * 4);
#pragma unroll
        for (int j = 0; j < 4; ++j) acc[j] += b2f(v[j]);
    }
    f32x4 b4 = *reinterpret_cast<const f32x4*>(bias + g * 4);
    float ndv = nd[n], nsv = ns[n];
    u16x4 o;
#pragma unroll
    for (int j = 0; j < 4; ++j) {
        float v = acc[j] * ndv + b4[j];
        v = (v > 0.0f) ? v : expm1f(v);
        o[j] = f2b(v * nsv);
    }
    *reinterpret_cast<u16x4*>(out + (size_t)n * 100 + g * 4) = o;
}

// gather2: h1s bf16 [NN][100] -> agg2b bf16 [NN][128] (raw sums, cols 0..99)
__global__ void gather2_kernel(const unsigned short* __restrict__ y, const int* __restrict__ row_ptr,
                               const int* __restrict__ col_src, unsigned short* __restrict__ out) {
    unsigned t = blockIdx.x * blockDim.x + threadIdx.x;
    if (t >= NN * 25u) return;
    unsigned n = t / 25u, g = t - n * 25u;
    int start = row_ptr[n], end = row_ptr[n + 1];
    f32x4 acc = (f32x4)(0.0f);
    for (int i = start; i < end; ++i) {
        int s = col_src[i];
        u16x4 v = *reinterpret_cast<const u16x4*>(y + (size_t)s * 100 + g * 4);
#pragma unroll
        for (int j = 0; j < 4; ++j) acc[j] += b2f(v[j]);
    }
    u16x4 o;
#pragma unroll
    for (int j = 0; j < 4; ++j) o[j] = f2b(acc[j]);
    *reinterpret_cast<u16x4*>(out + (size_t)n * 128 + g * 4) = o;
}

// gather3: y3 bf16 [NN][64] -> out f32 [NN][64];  out = sigmoid(sum*nd + b3)
__global__ void gather3_kernel(const unsigned short* __restrict__ y, const int* __restrict__ row_ptr,
                               const int* __restrict__ col_src, const float* __restrict__ nd,
                               const float* __restrict__ bias, float* __restrict__ out) {
    unsigned t = blockIdx.x * blockDim.x + threadIdx.x;
    if (t >= NN * 16u) return;
    unsigned n = t >> 4, g = t & 15u;
    int start = row_ptr[n], end = row_ptr[n + 1];
    f32x4 acc = (f32x4)(0.0f);
    for (int i = start; i < end; ++i) {
        int s = col_src[i];
        u16x4 v = *reinterpret_cast<const u16x4*>(y + (size_t)s * 64 + g * 4);
#pragma unroll
        for (int j = 0; j < 4; ++j) acc[j] += b2f(v[j]);
    }
    f32x4 b4 = *reinterpret_cast<const f32x4*>(bias + g * 4);
    float ndv = nd[n];
    f32x4 o;
#pragma unroll
    for (int j = 0; j < 4; ++j) {
        float v = acc[j] * ndv + b4[j];
        o[j] = 1.0f / (1.0f + expf(-v));
    }
    *reinterpret_cast<f32x4*>(out + (size_t)n * 64 + g * 4) = o;
}

// ================= launch =================

extern "C" void kernel_launch(void* const* d_in, const int* in_sizes, int n_in,
                              void* d_out, int out_size, void* d_ws, size_t ws_size,
                              hipStream_t stream) {
    const float* x    = (const float*)d_in[0];
    const int*   esrc = (const int*)d_in[1];
    const int*   edst = (const int*)d_in[2];
    const float* W1   = (const float*)d_in[3];
    const float* b1   = (const float*)d_in[4];
    const float* W2   = (const float*)d_in[5];
    const float* b2   = (const float*)d_in[6];
    const float* W3   = (const float*)d_in[7];
    const float* b3   = (const float*)d_in[8];
    float* out = (float*)d_out;

    // ---- workspace carving (256B-aligned regions) ----
    char* base = (char*)d_ws;
    size_t off = 0;
    auto alloc = [&](size_t bytes) -> void* {
        void* p = base + off;
        off += (bytes + 255) & ~(size_t)255;
        return p;
    };
    // region1: xb (bf16 [NN][128]) -> agg2b (bf16 [NN][128]) -> y3 (bf16 [NN][64])
    void* region1 = alloc((size_t)NN * 128 * 2);
    // region2: y1 (bf16 [NN][100]) -> h2b (bf16 [NN][224])
    void* region2 = alloc((size_t)NN * 224 * 2);
    // region3: h1s (bf16 [NN][100])
    void* region3 = alloc((size_t)NN * 100 * 2);
    float* ns       = (float*)alloc(NN * 4);
    float* nd       = (float*)alloc(NN * 4);
    int*   cnt_src  = (int*)alloc(NN * 4);
    int*   cnt_dst  = (int*)alloc(NN * 4);
    int*   row_ptr  = (int*)alloc((NN + 1) * 4);
    int*   fill_pos = (int*)alloc(NN * 4);
    int*   col_src  = (int*)alloc((size_t)NE * 4);
    int*   partials = (int*)alloc(512 * 4);
    unsigned short* W1f = (unsigned short*)alloc(4 * 7 * 512 * 2);    // K=128,N=112
    unsigned short* W2f = (unsigned short*)alloc(4 * 14 * 512 * 2);   // K=128,N=224
    unsigned short* W3f = (unsigned short*)alloc(7 * 4 * 512 * 2);    // K=224,N=64
    float* b2p = (float*)alloc(224 * 4);

    unsigned short* xb    = (unsigned short*)region1;
    unsigned short* agg2b = (unsigned short*)region1;
    unsigned short* y3    = (unsigned short*)region1;
    unsigned short* y1    = (unsigned short*)region2;
    unsigned short* h2b   = (unsigned short*)region2;
    unsigned short* h1s   = (unsigned short*)region3;

    const int BLK = 256;
    const int GEMM_GRID = (NN / 16 + 3) / 4;   // 6250 waves / 4 per block = 1563

    // ---- graph preprocessing ----
    hipMemsetAsync(cnt_src, 0, (size_t)NN * 4, stream);
    hipMemsetAsync(cnt_dst, 0, (size_t)NN * 4, stream);
    hist_kernel<<<grid_for(NE, BLK), BLK, 0, stream>>>(esrc, edst, cnt_src, cnt_dst);
    norm_kernel<<<grid_for(NN, BLK), BLK, 0, stream>>>(cnt_src, cnt_dst, ns, nd);
    block_sum_kernel<<<NB_SCAN, SCAN_BLK, 0, stream>>>(cnt_dst, partials);
    scan_partials_kernel<<<1, 512, 0, stream>>>(partials);
    block_scan_kernel<<<NB_SCAN, SCAN_BLK, 0, stream>>>(cnt_dst, partials, row_ptr, fill_pos);
    fill_bucketed_kernel<<<2048, BLK, 0, stream>>>(esrc, edst, fill_pos, col_src);

    // ---- bf16 prep ----
    f32_to_bf16_kernel<<<grid_for((long)NN * 128 / 4, BLK, 1 << 30), BLK, 0, stream>>>(
        x, xb, NN * 128 / 4);
    repack_kernel<128, 100, 7><<<grid_for(28 * 512, BLK), BLK, 0, stream>>>(W1, W1f, 28 * 512);
    repack_kernel<100, 200, 14><<<grid_for(56 * 512, BLK), BLK, 0, stream>>>(W2, W2f, 56 * 512);
    repack_kernel<200, 64, 4><<<grid_for(28 * 512, BLK), BLK, 0, stream>>>(W3, W3f, 28 * 512);
    padbias_kernel<<<1, 256, 0, stream>>>(b2, b2p, 200, 224);

    // ---- L1: y1 = (x @ W1) * ns  (bf16 [NN][100]) ----
    gemm_kernel<4, 7, 100, 2, 128><<<GEMM_GRID, BLK, 0, stream>>>(xb, W1f, ns, nullptr, y1);
    // h1s = elu(gather(y1)*nd + b1) * ns  (bf16 [NN][100])
    gather1_kernel<<<grid_for((long)NN * 25, BLK, 1 << 30), BLK, 0, stream>>>(
        y1, row_ptr, col_src, ns, nd, b1, h1s);

    // ---- L2: agg2 = gather(h1s)  (bf16 [NN][128], zero-padded) ----
    hipMemsetAsync(agg2b, 0, (size_t)NN * 128 * 2, stream);
    gather2_kernel<<<grid_for((long)NN * 25, BLK, 1 << 30), BLK, 0, stream>>>(
        h1s, row_ptr, col_src, agg2b);
    // h2 = elu((agg2 @ W2)*nd + b2)  (bf16 [NN][224], pads auto-zero)
    gemm_kernel<4, 14, 200, 1, 128><<<GEMM_GRID, BLK, 0, stream>>>(agg2b, W2f, nd, b2p, h2b);

    // ---- L3: y3 = (h2 @ W3) * ns  (bf16 [NN][64]) ----
    gemm_kernel<7, 4, 64, 2, 224><<<GEMM_GRID, BLK, 0, stream>>>(h2b, W3f, ns, nullptr, y3);
    // out = sigmoid(gather(y3)*nd + b3)
    gather3_kernel<<<grid_for((long)NN * 16, BLK, 1 << 30), BLK, 0, stream>>>(
        y3, row_ptr, col_src, nd, b3, out);
}